// Round 17
// baseline (143.102 us; speedup 1.0000x reference)
//
#include <hip/hip_runtime.h>
#include <hip/hip_bf16.h>

namespace {

constexpr int B     = 2;
constexpr int C     = 16;
constexpr int PREVC = 16;
constexpr int NPTS  = 16384;
constexpr int M1    = 4096;
constexpr int D1    = 4;
constexpr int CORR  = 15;
constexpr int FILT  = 15;
constexpr int CIN   = 48;
constexpr int CO0   = 32;
constexpr int O1    = 64;
constexpr int MS    = M1 + 1;        // 4097
constexpr int NSLOT = B * MS;        // 8194
constexpr int NPAIR = B * D1 * NPTS; // 131072
constexpr int BCAP  = 64;            // bucket capacity (mean 16, P(>64) ~ 0)
constexpr int GSTR  = 240;           // 225 idx2 + 15 idx1 (uint byte-offsets, +1 and *64 folded)
constexpr int SLAB  = 15360;         // per-point LDS stage: 15 k x 1024 B
constexpr float NEG = 0.1f;

// ---- workspace layout (float units) ----
constexpr size_t OFF_SP1   = 0;                               // splat1 [slot][32] f32
constexpr size_t SZ_SP1    = (size_t)NSLOT * 32;
constexpr size_t OFF_SP2   = OFF_SP1 + SZ_SP1;                // splat2 [slot][16] f32
constexpr size_t SZ_SP2    = (size_t)NSLOT * 16;
constexpr size_t OFF_P     = OFF_SP2 + SZ_SP2;                // P bf16 [b][k][m][32]
constexpr size_t SZ_PQ     = (size_t)B * CORR * MS * 32 / 2;
constexpr size_t OFF_Q     = OFF_P + SZ_PQ;                   // Q bf16
constexpr size_t OFF_CWT   = OFF_Q + SZ_PQ;                   // cwT [k][i48][o32] f32
constexpr size_t SZ_CWT    = (size_t)CORR * CIN * 32;
constexpr size_t OFF_W0R   = OFF_CWT + SZ_CWT;                // W0r [cf512][o64] f32
constexpr size_t SZ_W0R    = 512 * 64;
constexpr size_t OFF_PREVT = OFF_W0R + SZ_W0R;                // prevT [b][n][16] f32
constexpr size_t SZ_PREVT  = (size_t)B * NPTS * 16;
constexpr size_t OFF_CNT   = OFF_PREVT + SZ_PREVT;            // counts (int)
constexpr size_t SZ_CNT    = 8208;                            // >= NSLOT, padded
constexpr size_t OFF_REC   = OFF_CNT + SZ_CNT;                // rec (int) [slot][64]
constexpr size_t SZ_REC    = (size_t)NSLOT * BCAP;
constexpr size_t OFF_GT    = OFF_REC + SZ_REC;                // gT (uint) [b*M1][240]
constexpr size_t SZ_GT     = (size_t)B * M1 * GSTR;

__device__ __forceinline__ float leaky(float v) { return v > 0.f ? v : NEG * v; }
__device__ __forceinline__ float bflo(unsigned u) { return __uint_as_float(u << 16); }
__device__ __forceinline__ float bfhi(unsigned u) { return __uint_as_float(u & 0xffff0000u); }

__device__ __forceinline__ void gload_lds16(const void* g, void* l) {
  __builtin_amdgcn_global_load_lds(
      (const __attribute__((address_space(1))) unsigned int*)g,
      (__attribute__((address_space(3))) unsigned int*)l, 16, 0, 0);
}

// ===== fused prep: count+bucket-scatter | prev transpose | weight prep | pc transpose =====
__global__ __launch_bounds__(256) void k_pre(const int* __restrict__ lo,
                                             const float* __restrict__ prev,
                                             const float* __restrict__ cw0,
                                             const float* __restrict__ bw0,
                                             const int* __restrict__ pc1,
                                             const int* __restrict__ pc2,
                                             int* __restrict__ counts,
                                             int* __restrict__ rec,
                                             float* __restrict__ prevT,
                                             float* __restrict__ cwT,
                                             float* __restrict__ W0r,
                                             unsigned int* __restrict__ gT) {
  int bx = blockIdx.x, tid = threadIdx.x;
  if (bx < 512) {                       // ---- count + direct bucket scatter ----
    int t = bx * 256 + tid;
    int slot = lo[t] + 1;
    int pos = atomicAdd(counts + slot, 1);
    if (pos < BCAP) rec[slot * BCAP + pos] = t;
  } else if (bx < 1024) {               // ---- prev transpose [b][16][N] -> [b][n][16] ----
    __shared__ float tile[16][65];
    int bb = bx - 512;
    int b = bb >> 8, n0 = (bb & 255) * 64;
    for (int e = tid; e < 1024; e += 256) {
      int ln = e & 63, r = e >> 6;
      tile[r][ln] = prev[((size_t)b * PREVC + r) * NPTS + n0 + ln];
    }
    __syncthreads();
    for (int e = tid; e < 1024; e += 256) {
      int c = e & 15, nn = e >> 4;
      prevT[((size_t)b * NPTS + n0 + nn) * 16 + c] = tile[c][nn];
    }
  } else if (bx < 1243) {               // ---- weight prep ----
    int e = (bx - 1024) * 256 + tid;
    if (e < CORR * CIN * 32) {
      int o = e & 31, i = (e >> 5) % CIN, k = e / (CIN * 32);
      cwT[e] = cw0[((size_t)o * CIN + i) * CORR + k];
    }
    int e2 = e - CORR * CIN * 32;
    if (e2 >= 0 && e2 < 512 * 64) {
      int o3 = e2 & 63, cf = e2 >> 6, c = cf >> 4, f = cf & 15;
      W0r[e2] = (f < FILT) ? bw0[((size_t)o3 * CO0 + c) * FILT + f] : 0.f;
    }
  } else {                              // ---- pc1/pc2 transpose -> gT (uint byte offsets) ----
    __shared__ int tile[16][65];
    int t = bx - 1243;
    int n0 = (t & 63) * 64;
    int rest = t >> 6;                  // 0..31
    int b = rest & 1;
    int rt = rest >> 1;                 // 0..15
    const int* src; int r0, nr, doff;
    if (rt < 15) { src = pc2 + (size_t)b * FILT * CORR * M1; r0 = rt * 16;
                   nr = min(16, FILT * CORR - r0); doff = 0; }
    else         { src = pc1 + (size_t)b * CORR * M1; r0 = 0; nr = CORR; doff = 225; }
    for (int e = tid; e < nr * 64; e += 256) {
      int ln = e & 63, r = e >> 6;
      tile[r][ln] = src[(size_t)(r0 + r) * M1 + n0 + ln] + 1;
    }
    __syncthreads();
    for (int e = tid; e < 1024; e += 256) {
      int rr = e & 15, nn = e >> 4;
      if (rr < nr)
        gT[((size_t)b * M1 + n0 + nn) * GSTR + doff + r0 + rr] =
            (unsigned int)(tile[rr][nn] * 64);   // pre-scaled byte offset (row = 64B)
    }
  }
}

// ===== per-slot bucket summation + normalize + feat fills =====
__global__ __launch_bounds__(256) void k_sum(const int* __restrict__ rec,
                                             const int* __restrict__ counts,
                                             const float* __restrict__ bary,
                                             const float* __restrict__ prevT,
                                             const float* __restrict__ feat1,
                                             const float* __restrict__ feat2,
                                             float* __restrict__ splat1,
                                             float* __restrict__ splat2) {
  int tid = threadIdx.x;
  int s = blockIdx.x * 4 + (tid >> 6);
  if (s >= NSLOT) return;
  int lane = tid & 63, c = lane & 15, g = lane >> 4;
  int cnt = min(counts[s], BCAP);
  const int* bucket = rec + (size_t)s * BCAP;
  float acc = 0.f, wsum = 0.f;
  for (int e = g; e < cnt; e += 4) {
    int t = bucket[e];
    float w = bary[t];
    int n = t & (NPTS - 1);
    int b = t >> 16;                    // D1*NPTS = 65536
    acc += w * prevT[((size_t)b * NPTS + n) * 16 + c];
    wsum += w;
  }
  acc  += __shfl_down(acc, 32);  acc  += __shfl_down(acc, 16);
  wsum += __shfl_down(wsum, 32); wsum += __shfl_down(wsum, 16);
  if (lane < 16) {
    int m = s % MS, b2 = s / MS;
    float scale = 1.f / (wsum + 1e-5f);
    splat1[(size_t)s * 32 + c] = acc * scale;
    float f1 = (m == 0) ? 0.f : feat1[((size_t)b2 * C + c) * M1 + (m - 1)];
    splat1[(size_t)s * 32 + 16 + c] = f1;
    float f2 = (m == 0) ? 0.f : feat2[((size_t)b2 * C + c) * M1 + (m - 1)];
    splat2[(size_t)s * 16 + c] = f2;
  }
}

// ===== per-slot projections P, Q (bf16 out) — multipass, 64 m-slots per block =====
__global__ __launch_bounds__(256) void k_pq(const float* __restrict__ sp1,
                                            const float* __restrict__ sp2,
                                            const float* __restrict__ cwT,
                                            __hip_bfloat16* __restrict__ Pt,
                                            __hip_bfloat16* __restrict__ Qt) {
  __shared__ float wk[CIN][33];
  int k = blockIdx.y, b = blockIdx.z;
  int tid = threadIdx.x;
  int m0 = blockIdx.x * 64;
  int mm = tid >> 4, o2 = tid & 15;
  for (int e = tid; e < CIN * 32; e += 256)
    wk[e >> 5][e & 31] = cwT[(size_t)k * CIN * 32 + e];
  __syncthreads();
  int oa = o2 * 2, ob = oa + 1;
#pragma unroll
  for (int mt = 0; mt < 4; ++mt) {
    int m = m0 + mt * 16 + mm;
    if (m >= MS) continue;
    const float* s1 = sp1 + ((size_t)b * MS + m) * 32;
    const float* s2 = sp2 + ((size_t)b * MS + m) * 16;
    float q0 = 0, q1 = 0, p0 = 0, p1 = 0;
#pragma unroll
    for (int i4 = 0; i4 < 8; ++i4) {
      float4 s = *(const float4*)(s1 + i4 * 4);
      q0 += s.x * wk[i4*4+0][oa] + s.y * wk[i4*4+1][oa] + s.z * wk[i4*4+2][oa] + s.w * wk[i4*4+3][oa];
      q1 += s.x * wk[i4*4+0][ob] + s.y * wk[i4*4+1][ob] + s.z * wk[i4*4+2][ob] + s.w * wk[i4*4+3][ob];
    }
#pragma unroll
    for (int i4 = 0; i4 < 4; ++i4) {
      float4 s = *(const float4*)(s2 + i4 * 4);
      p0 += s.x * wk[32+i4*4+0][oa] + s.y * wk[32+i4*4+1][oa] + s.z * wk[32+i4*4+2][oa] + s.w * wk[32+i4*4+3][oa];
      p1 += s.x * wk[32+i4*4+0][ob] + s.y * wk[32+i4*4+1][ob] + s.z * wk[32+i4*4+2][ob] + s.w * wk[32+i4*4+3][ob];
    }
    size_t base = ((size_t)(b * CORR + k) * MS + m) * 32;
    __hip_bfloat162 qq, pp;
    qq.x = __float2bfloat16(q0); qq.y = __float2bfloat16(q1);
    pp.x = __float2bfloat16(p0); pp.y = __float2bfloat16(p1);
    *reinterpret_cast<__hip_bfloat162*>(Qt + base + oa) = qq;
    *reinterpret_cast<__hip_bfloat162*>(Pt + base + oa) = pp;
  }
}

// ===== FUSED gather + corr-conv + blur conv; 4 points/block =====
// Stage-1 via global_load_lds DMA: 15 fire-and-forget 1KB stages per wave (full
// MLP with ZERO result VGPRs -- the register allocator can no longer cap it).
// LDS 65536B -> 2 blocks/CU; per-point 15360B slab, overlaid after consumption:
//   slab_p + 0     : stage k-rows (15x1024) | after: xls_p f32[16][36] (2304B)
//   slab_p + 4096 + p*80 : hT_p bf16[512] (p*80 staggers banks for stage-3 reads)
//   slab_p + 5632  : p1s_p f32[32]
//   slab0  + 6144  : wch f32[32][68] (8704B, block-shared, barrier-protected)
//   slab1  + 6144  : y0s f32[4][68]
//   61440..65536   : idxs uint[4][240] | after: parts f32[4][4][16][4]
__global__ __launch_bounds__(256, 2) void k_gather(const __hip_bfloat16* __restrict__ Pt,
                                                   const __hip_bfloat16* __restrict__ Qt,
                                                   const unsigned int* __restrict__ gT,
                                                   const float* __restrict__ cw1,
                                                   const float* __restrict__ cb0,
                                                   const float* __restrict__ cb1,
                                                   const float* __restrict__ W0r,
                                                   const float* __restrict__ bb0,
                                                   const float* __restrict__ bw1,
                                                   const float* __restrict__ bb1,
                                                   float* __restrict__ out) {
  __shared__ __attribute__((aligned(16))) char smem[65536];
  unsigned int* idxs = (unsigned int*)(smem + 61440);               // [4][240]
  float* parts       = (float*)(smem + 61440);                      // [4][4][16][4]
  float* wch         = (float*)(smem + 6144);                       // [32][68]
  float* y0s         = (float*)(smem + SLAB + 6144);                // [4][68]

  int bid = blockIdx.x;                // 2048 blocks
  int b = (bid >> 2) & 1;              // bid%8 {0..3}->b=0 (XCD 0-3), {4..7}->b=1
  int r = bid & 3, x = bid >> 3;
  int n0 = (r << 10) | (x << 2);
  int pt0 = (b << 12) | n0;
  int tid = threadIdx.x;

  for (int e = tid; e < 240; e += 256) {     // 4 pts x 60 uint4 of offsets
    int pl = e / 60, d = e - pl * 60;
    ((uint4*)(idxs + pl * GSTR))[d] =
        ((const uint4*)(gT + (size_t)(pt0 + pl) * GSTR))[d];
  }
  __syncthreads();

  int pl = tid >> 6, lane = tid & 63;
  char* slabp = smem + pl * SLAB;
  float* xlsP = (float*)slabp;                                      // [16][36]
  __hip_bfloat16* hTp = (__hip_bfloat16*)(slabp + 4096 + pl * 80);  // [512]
  float* p1sP = (float*)(slabp + 5632);                             // [32]

  // ---- stage 1: DMA all 15 k-slices to LDS (fire-and-forget), then reduce ----
  {
    int f = lane >> 2, o4 = lane & 3;  // lane = f*4+o4 -> LDS chunk at lane*16
    const char* baseg = (const char*)((f < CORR ? Pt : Qt) + (size_t)b * CORR * MS * 32);
    const unsigned int* ip = idxs + pl * GSTR + (f < CORR ? f * CORR : 225);
    unsigned int lo = (unsigned int)(o4 * 16);
#pragma unroll
    for (int k = 0; k < CORR; ++k) {
      unsigned int off = ip[k] + (unsigned int)(k * MS * 64) + lo;
      gload_lds16(baseg + off, slabp + k * 1024);
    }
    asm volatile("s_waitcnt vmcnt(0)" ::: "memory");
    __builtin_amdgcn_sched_barrier(0);

    float a[8] = {};
#pragma unroll
    for (int k = 0; k < CORR; ++k) {
      uint4 d = *(const uint4*)(slabp + k * 1024 + lane * 16);
      a[0] += bflo(d.x); a[1] += bfhi(d.x);
      a[2] += bflo(d.y); a[3] += bfhi(d.y);
      a[4] += bflo(d.z); a[5] += bfhi(d.z);
      a[6] += bflo(d.w); a[7] += bfhi(d.w);
    }
    if (f == CORR) {
#pragma unroll
      for (int j = 0; j < 8; ++j)
        p1sP[o4 * 8 + j] = a[j] + cb0[o4 * 8 + j];
    }
    __syncthreads();
    if (f < CORR) {
#pragma unroll
      for (int j = 0; j < 8; ++j)
        xlsP[f * 36 + o4 * 8 + j] = leaky(a[j] + p1sP[o4 * 8 + j]);
    }
  }
  __syncthreads();

  // ---- stage 2: 1x1 conv, 8 f's per thread, h -> LDS (bf16) ----
  {
    int o = lane & 31, fh = lane >> 5;
    const float* wrow = cw1 + o * CO0;           // L1-resident (4 KB)
    float bias = cb1[o];
    float h[8];
#pragma unroll
    for (int j = 0; j < 8; ++j) {
      float hh = bias;
#pragma unroll
      for (int c4 = 0; c4 < 8; ++c4) {
        float4 xv = *(const float4*)&xlsP[(fh * 8 + j) * 36 + c4 * 4];
        float4 w  = *(const float4*)(wrow + c4 * 4);
        hh += w.x * xv.x + w.y * xv.y + w.z * xv.z + w.w * xv.w;
      }
      h[j] = leaky(hh);
    }
    if (fh == 1) h[7] = 0.f;                     // cf slot f==15 pad
    union { __hip_bfloat16 hb[8]; uint4 u; } pk;
#pragma unroll
    for (int j = 0; j < 8; ++j) pk.hb[j] = __float2bfloat16(h[j]);
    *(uint4*)(hTp + o * 16 + fh * 8) = pk.u;
  }

  // ---- stage 3: blur GEMM y0 = leaky(W0 h + b0), W0r chunked through LDS ----
  int og = tid & 15, bpl = (tid >> 4) & 3, rep = tid >> 6;
  const __hip_bfloat16* hTb = (const __hip_bfloat16*)(smem + bpl * SLAB + 4096 + bpl * 80);
  float acc[4] = {};
  for (int kc = 0; kc < 512; kc += 32) {
    __syncthreads();                             // protect wch (and first: xls/hT writers done)
    for (int e = tid; e < 512; e += 256) {       // 32 rows x 16 float4
      int rr = e >> 4, c4 = e & 15;
      *(float4*)&wch[rr * 68 + c4 * 4] = *(const float4*)(W0r + (size_t)(kc + rr) * 64 + c4 * 4);
    }
    __syncthreads();
#pragma unroll
    for (int i = 0; i < 8; ++i) {
      int kk = rep + i * 4;
      float hv = __bfloat162float(hTb[kc + kk]);
      float4 w = *(const float4*)&wch[kk * 68 + og * 4];
      acc[0] += w.x * hv; acc[1] += w.y * hv; acc[2] += w.z * hv; acc[3] += w.w * hv;
    }
  }
  __syncthreads();
  *(float4*)&parts[((rep * 4 + bpl) * 16 + og) * 4] = make_float4(acc[0], acc[1], acc[2], acc[3]);
  __syncthreads();

  {
    int ypl = tid & 3, yo3 = tid >> 2;
    int og2 = yo3 >> 2, comp = yo3 & 3;
    float y0 = bb0[yo3];
#pragma unroll
    for (int rp = 0; rp < 4; ++rp)
      y0 += parts[((rp * 4 + ypl) * 16 + og2) * 4 + comp];
    y0s[ypl * 68 + yo3] = leaky(y0);
  }
  __syncthreads();

  // ---- stage 4: final 1x1 (no relu), direct store ----
  {
    int fpl = tid & 3, fo1 = tid >> 2;
    const float* w1row = bw1 + fo1 * 64;         // L1/L2-resident (16 KB)
    float y1 = bb1[fo1];
#pragma unroll
    for (int c4 = 0; c4 < 16; ++c4) {
      float4 w = *(const float4*)(w1row + c4 * 4);
      y1 += w.x * y0s[fpl * 68 + c4 * 4 + 0] + w.y * y0s[fpl * 68 + c4 * 4 + 1] +
            w.z * y0s[fpl * 68 + c4 * 4 + 2] + w.w * y0s[fpl * 68 + c4 * 4 + 3];
    }
    out[((size_t)(b * O1 + fo1)) * M1 + n0 + fpl] = y1;
  }
}

}  // namespace

extern "C" void kernel_launch(void* const* d_in, const int* in_sizes, int n_in,
                              void* d_out, int out_size, void* d_ws, size_t ws_size,
                              hipStream_t stream) {
  const float* feat1 = (const float*)d_in[0];
  const float* feat2 = (const float*)d_in[1];
  const float* prev  = (const float*)d_in[2];
  const float* bary  = (const float*)d_in[3];
  const float* cw0   = (const float*)d_in[4];
  const float* cb0   = (const float*)d_in[5];
  const float* cw1   = (const float*)d_in[6];
  const float* cb1   = (const float*)d_in[7];
  const float* bw0   = (const float*)d_in[8];
  const float* bb0   = (const float*)d_in[9];
  const float* bw1   = (const float*)d_in[10];
  const float* bb1   = (const float*)d_in[11];
  const int* lo  = (const int*)d_in[12];
  const int* pc1 = (const int*)d_in[13];
  const int* pc2 = (const int*)d_in[14];

  float* ws = (float*)d_ws;
  float* splat1 = ws + OFF_SP1;
  float* splat2 = ws + OFF_SP2;
  __hip_bfloat16* Pt = (__hip_bfloat16*)(ws + OFF_P);
  __hip_bfloat16* Qt = (__hip_bfloat16*)(ws + OFF_Q);
  float* cwT   = ws + OFF_CWT;
  float* W0r   = ws + OFF_W0R;
  float* prevT = ws + OFF_PREVT;
  int* counts  = (int*)(ws + OFF_CNT);
  int* rec     = (int*)(ws + OFF_REC);
  unsigned int* gT = (unsigned int*)(ws + OFF_GT);
  float* out   = (float*)d_out;

  hipMemsetAsync(counts, 0, NSLOT * sizeof(int), stream);

  hipLaunchKernelGGL(k_pre, dim3(1243 + 2048), dim3(256), 0, stream,
                     lo, prev, cw0, bw0, pc1, pc2, counts, rec, prevT, cwT, W0r, gT);
  hipLaunchKernelGGL(k_sum, dim3((NSLOT + 3) / 4), dim3(256), 0, stream,
                     rec, counts, bary, prevT, feat1, feat2, splat1, splat2);
  hipLaunchKernelGGL(k_pq, dim3((MS + 63) / 64, CORR, B), dim3(256), 0, stream,
                     splat1, splat2, cwT, Pt, Qt);
  hipLaunchKernelGGL(k_gather, dim3(B * M1 / 4), dim3(256), 0, stream,
                     Pt, Qt, gT, cw1, cb0, cb1, W0r, bb0, bw1, bb1, out);
}

// Round 18
// 111.877 us; speedup vs baseline: 1.2791x; 1.2791x over previous
//
#include <hip/hip_runtime.h>
#include <hip/hip_bf16.h>

namespace {

constexpr int B     = 2;
constexpr int C     = 16;
constexpr int PREVC = 16;
constexpr int NPTS  = 16384;
constexpr int M1    = 4096;
constexpr int D1    = 4;
constexpr int CORR  = 15;
constexpr int FILT  = 15;
constexpr int CIN   = 48;
constexpr int CO0   = 32;
constexpr int O1    = 64;
constexpr int MS    = M1 + 1;        // 4097
constexpr int NSLOT = B * MS;        // 8194
constexpr int NPAIR = B * D1 * NPTS; // 131072
constexpr int BCAP  = 64;            // bucket capacity (mean 16, P(>64) ~ 0)
constexpr int GSTR  = 240;           // 225 idx2 + 15 idx1 (uint byte-offsets, +1 and *64 folded)
constexpr float NEG = 0.1f;

// ---- workspace layout (float units) ----
constexpr size_t OFF_SP1   = 0;                               // splat1 [slot][32] f32
constexpr size_t SZ_SP1    = (size_t)NSLOT * 32;
constexpr size_t OFF_SP2   = OFF_SP1 + SZ_SP1;                // splat2 [slot][16] f32
constexpr size_t SZ_SP2    = (size_t)NSLOT * 16;
constexpr size_t OFF_P     = OFF_SP2 + SZ_SP2;                // P bf16 [b][k][m][32]
constexpr size_t SZ_PQ     = (size_t)B * CORR * MS * 32 / 2;
constexpr size_t OFF_Q     = OFF_P + SZ_PQ;                   // Q bf16
constexpr size_t OFF_CWT   = OFF_Q + SZ_PQ;                   // cwT [k][i48][o32] f32
constexpr size_t SZ_CWT    = (size_t)CORR * CIN * 32;
constexpr size_t OFF_W0R   = OFF_CWT + SZ_CWT;                // W0r [cf512][o64] f32
constexpr size_t SZ_W0R    = 512 * 64;
constexpr size_t OFF_PREVT = OFF_W0R + SZ_W0R;                // prevT [b][n][16] f32
constexpr size_t SZ_PREVT  = (size_t)B * NPTS * 16;
constexpr size_t OFF_CNT   = OFF_PREVT + SZ_PREVT;            // counts (int)
constexpr size_t SZ_CNT    = 8208;                            // >= NSLOT, padded
constexpr size_t OFF_REC   = OFF_CNT + SZ_CNT;                // rec (int) [slot][64]
constexpr size_t SZ_REC    = (size_t)NSLOT * BCAP;
constexpr size_t OFF_GT    = OFF_REC + SZ_REC;                // gT (uint) [b*M1][240]
constexpr size_t SZ_GT     = (size_t)B * M1 * GSTR;

__device__ __forceinline__ float leaky(float v) { return v > 0.f ? v : NEG * v; }
__device__ __forceinline__ float bflo(unsigned u) { return __uint_as_float(u << 16); }
__device__ __forceinline__ float bfhi(unsigned u) { return __uint_as_float(u & 0xffff0000u); }

// ===== fused prep: count+bucket-scatter | prev transpose | weight prep | pc transpose =====
__global__ __launch_bounds__(256) void k_pre(const int* __restrict__ lo,
                                             const float* __restrict__ prev,
                                             const float* __restrict__ cw0,
                                             const float* __restrict__ bw0,
                                             const int* __restrict__ pc1,
                                             const int* __restrict__ pc2,
                                             int* __restrict__ counts,
                                             int* __restrict__ rec,
                                             float* __restrict__ prevT,
                                             float* __restrict__ cwT,
                                             float* __restrict__ W0r,
                                             unsigned int* __restrict__ gT) {
  int bx = blockIdx.x, tid = threadIdx.x;
  if (bx < 512) {                       // ---- count + direct bucket scatter ----
    int t = bx * 256 + tid;
    int slot = lo[t] + 1;
    int pos = atomicAdd(counts + slot, 1);
    if (pos < BCAP) rec[slot * BCAP + pos] = t;
  } else if (bx < 1024) {               // ---- prev transpose [b][16][N] -> [b][n][16] ----
    __shared__ float tile[16][65];
    int bb = bx - 512;
    int b = bb >> 8, n0 = (bb & 255) * 64;
    for (int e = tid; e < 1024; e += 256) {
      int ln = e & 63, r = e >> 6;
      tile[r][ln] = prev[((size_t)b * PREVC + r) * NPTS + n0 + ln];
    }
    __syncthreads();
    for (int e = tid; e < 1024; e += 256) {
      int c = e & 15, nn = e >> 4;
      prevT[((size_t)b * NPTS + n0 + nn) * 16 + c] = tile[c][nn];
    }
  } else if (bx < 1243) {               // ---- weight prep ----
    int e = (bx - 1024) * 256 + tid;
    if (e < CORR * CIN * 32) {
      int o = e & 31, i = (e >> 5) % CIN, k = e / (CIN * 32);
      cwT[e] = cw0[((size_t)o * CIN + i) * CORR + k];
    }
    int e2 = e - CORR * CIN * 32;
    if (e2 >= 0 && e2 < 512 * 64) {
      int o3 = e2 & 63, cf = e2 >> 6, c = cf >> 4, f = cf & 15;
      W0r[e2] = (f < FILT) ? bw0[((size_t)o3 * CO0 + c) * FILT + f] : 0.f;
    }
  } else {                              // ---- pc1/pc2 transpose -> gT (uint byte offsets) ----
    __shared__ int tile[16][65];
    int t = bx - 1243;
    int n0 = (t & 63) * 64;
    int rest = t >> 6;                  // 0..31
    int b = rest & 1;
    int rt = rest >> 1;                 // 0..15
    const int* src; int r0, nr, doff;
    if (rt < 15) { src = pc2 + (size_t)b * FILT * CORR * M1; r0 = rt * 16;
                   nr = min(16, FILT * CORR - r0); doff = 0; }
    else         { src = pc1 + (size_t)b * CORR * M1; r0 = 0; nr = CORR; doff = 225; }
    for (int e = tid; e < nr * 64; e += 256) {
      int ln = e & 63, r = e >> 6;
      tile[r][ln] = src[(size_t)(r0 + r) * M1 + n0 + ln] + 1;
    }
    __syncthreads();
    for (int e = tid; e < 1024; e += 256) {
      int rr = e & 15, nn = e >> 4;
      if (rr < nr)
        gT[((size_t)b * M1 + n0 + nn) * GSTR + doff + r0 + rr] =
            (unsigned int)(tile[rr][nn] * 64);   // pre-scaled byte offset (row = 64B)
    }
  }
}

// ===== per-slot bucket summation + normalize + feat fills =====
__global__ __launch_bounds__(256) void k_sum(const int* __restrict__ rec,
                                             const int* __restrict__ counts,
                                             const float* __restrict__ bary,
                                             const float* __restrict__ prevT,
                                             const float* __restrict__ feat1,
                                             const float* __restrict__ feat2,
                                             float* __restrict__ splat1,
                                             float* __restrict__ splat2) {
  int tid = threadIdx.x;
  int s = blockIdx.x * 4 + (tid >> 6);
  if (s >= NSLOT) return;
  int lane = tid & 63, c = lane & 15, g = lane >> 4;
  int cnt = min(counts[s], BCAP);
  const int* bucket = rec + (size_t)s * BCAP;
  float acc = 0.f, wsum = 0.f;
  for (int e = g; e < cnt; e += 4) {
    int t = bucket[e];
    float w = bary[t];
    int n = t & (NPTS - 1);
    int b = t >> 16;                    // D1*NPTS = 65536
    acc += w * prevT[((size_t)b * NPTS + n) * 16 + c];
    wsum += w;
  }
  acc  += __shfl_down(acc, 32);  acc  += __shfl_down(acc, 16);
  wsum += __shfl_down(wsum, 32); wsum += __shfl_down(wsum, 16);
  if (lane < 16) {
    int m = s % MS, b2 = s / MS;
    float scale = 1.f / (wsum + 1e-5f);
    splat1[(size_t)s * 32 + c] = acc * scale;
    float f1 = (m == 0) ? 0.f : feat1[((size_t)b2 * C + c) * M1 + (m - 1)];
    splat1[(size_t)s * 32 + 16 + c] = f1;
    float f2 = (m == 0) ? 0.f : feat2[((size_t)b2 * C + c) * M1 + (m - 1)];
    splat2[(size_t)s * 16 + c] = f2;
  }
}

// ===== per-slot projections P, Q (bf16 out) — multipass, 64 m-slots per block =====
// grid (65, 15, 2): weights staged ONCE per 64 m's (4x fewer blocks / weight reads
// than the 16-m version; splat rows are L1-broadcast across the 16 o2-threads).
__global__ __launch_bounds__(256) void k_pq(const float* __restrict__ sp1,
                                            const float* __restrict__ sp2,
                                            const float* __restrict__ cwT,
                                            __hip_bfloat16* __restrict__ Pt,
                                            __hip_bfloat16* __restrict__ Qt) {
  __shared__ float wk[CIN][33];
  int k = blockIdx.y, b = blockIdx.z;
  int tid = threadIdx.x;
  int m0 = blockIdx.x * 64;
  int mm = tid >> 4, o2 = tid & 15;
  for (int e = tid; e < CIN * 32; e += 256)
    wk[e >> 5][e & 31] = cwT[(size_t)k * CIN * 32 + e];
  __syncthreads();
  int oa = o2 * 2, ob = oa + 1;
#pragma unroll
  for (int mt = 0; mt < 4; ++mt) {
    int m = m0 + mt * 16 + mm;
    if (m >= MS) continue;
    const float* s1 = sp1 + ((size_t)b * MS + m) * 32;
    const float* s2 = sp2 + ((size_t)b * MS + m) * 16;
    float q0 = 0, q1 = 0, p0 = 0, p1 = 0;
#pragma unroll
    for (int i4 = 0; i4 < 8; ++i4) {
      float4 s = *(const float4*)(s1 + i4 * 4);
      q0 += s.x * wk[i4*4+0][oa] + s.y * wk[i4*4+1][oa] + s.z * wk[i4*4+2][oa] + s.w * wk[i4*4+3][oa];
      q1 += s.x * wk[i4*4+0][ob] + s.y * wk[i4*4+1][ob] + s.z * wk[i4*4+2][ob] + s.w * wk[i4*4+3][ob];
    }
#pragma unroll
    for (int i4 = 0; i4 < 4; ++i4) {
      float4 s = *(const float4*)(s2 + i4 * 4);
      p0 += s.x * wk[32+i4*4+0][oa] + s.y * wk[32+i4*4+1][oa] + s.z * wk[32+i4*4+2][oa] + s.w * wk[32+i4*4+3][oa];
      p1 += s.x * wk[32+i4*4+0][ob] + s.y * wk[32+i4*4+1][ob] + s.z * wk[32+i4*4+2][ob] + s.w * wk[32+i4*4+3][ob];
    }
    size_t base = ((size_t)(b * CORR + k) * MS + m) * 32;
    __hip_bfloat162 qq, pp;
    qq.x = __float2bfloat16(q0); qq.y = __float2bfloat16(q1);
    pp.x = __float2bfloat16(p0); pp.y = __float2bfloat16(p1);
    *reinterpret_cast<__hip_bfloat162*>(Qt + base + oa) = qq;
    *reinterpret_cast<__hip_bfloat162*>(Pt + base + oa) = pp;
  }
}

// ===== FUSED gather + corr-conv + blur conv; 4 points/block (r10/r16 structure) =====
// Stage-1 loads are plain: r15 (nt loads) and r17 (global_load_lds DMA) both
// regressed; r11/r12/r13 register-MLP attempts all pinned at 64 VGPR or spilled.
// The random-64B-row gather is at its service-path floor in this decomposition.
// LDS plan (19072 B, 8 blocks/CU):
//   [0,     4096)  idxs uint[4][240]        | after stage2: parts f32[4][4][16][4]
//   [4096,  4608)  p1s  f32 [4][32]
//   [4608, 13824)  xls  f32 [4][16][36]     | in blur: wch f32 [32][68] (8704 B)
//   [13824,17984)  hT   bf16 [4][520]       (520-stride: bpl rows in distinct banks)
//   [17984,19072)  y0s  f32 [4][68]
__global__ __launch_bounds__(256, 4) void k_gather(const __hip_bfloat16* __restrict__ Pt,
                                                   const __hip_bfloat16* __restrict__ Qt,
                                                   const unsigned int* __restrict__ gT,
                                                   const float* __restrict__ cw1,
                                                   const float* __restrict__ cb0,
                                                   const float* __restrict__ cb1,
                                                   const float* __restrict__ W0r,
                                                   const float* __restrict__ bb0,
                                                   const float* __restrict__ bw1,
                                                   const float* __restrict__ bb1,
                                                   float* __restrict__ out) {
  __shared__ __attribute__((aligned(16))) char smem[19072];
  unsigned int* idxs = (unsigned int*)smem;                         // [4][240]
  float* parts       = (float*)smem;                                // [4][4][16][4]
  float* p1s         = (float*)(smem + 4096);                       // [4][32]
  float* xls         = (float*)(smem + 4608);                       // [4][16][36]
  float* wch         = (float*)(smem + 4608);                       // [32][68]
  __hip_bfloat16* hT = (__hip_bfloat16*)(smem + 13824);             // [4][520]
  float* y0s         = (float*)(smem + 17984);                      // [4][68]

  int bid = blockIdx.x;                // 2048 blocks
  int b = (bid >> 2) & 1;              // bid%8 {0..3}->b=0 (XCD 0-3), {4..7}->b=1
  int r = bid & 3, x = bid >> 3;
  int n0 = (r << 10) | (x << 2);
  int pt0 = (b << 12) | n0;
  int tid = threadIdx.x;

  for (int e = tid; e < 240; e += 256) {     // 4 pts x 60 uint4 of offsets
    int pl = e / 60, d = e - pl * 60;
    ((uint4*)(idxs + pl * GSTR))[d] =
        ((const uint4*)(gT + (size_t)(pt0 + pl) * GSTR))[d];
  }
  __syncthreads();

  int pl = tid >> 6, lane = tid & 63;

  // ---- stage 1: gather-sum, 15 loads in flight, SGPR base + 32-bit voffset ----
  {
    int f = lane >> 2, o4 = lane & 3;  // 4 lanes per row -> one 64B line per (f,k)
    const char* base = (const char*)((f < CORR ? Pt : Qt) + (size_t)b * CORR * MS * 32);
    const unsigned int* ip = idxs + pl * GSTR + (f < CORR ? f * CORR : 225);
    unsigned int lo = (unsigned int)(o4 * 16);
    float a[8] = {};
#pragma unroll
    for (int k = 0; k < CORR; ++k) {
      unsigned int off = ip[k] + (unsigned int)(k * MS * 64) + lo;
      uint4 d = *(const uint4*)(base + off);
      a[0] += bflo(d.x); a[1] += bfhi(d.x);
      a[2] += bflo(d.y); a[3] += bfhi(d.y);
      a[4] += bflo(d.z); a[5] += bfhi(d.z);
      a[6] += bflo(d.w); a[7] += bfhi(d.w);
    }
    if (f == CORR) {
#pragma unroll
      for (int j = 0; j < 8; ++j)
        p1s[pl * 32 + o4 * 8 + j] = a[j] + cb0[o4 * 8 + j];
    }
    __syncthreads();
    if (f < CORR) {
#pragma unroll
      for (int j = 0; j < 8; ++j)
        xls[pl * 576 + f * 36 + o4 * 8 + j] = leaky(a[j] + p1s[pl * 32 + o4 * 8 + j]);
    }
  }
  __syncthreads();

  // ---- stage 2: 1x1 conv, 8 f's per thread, h -> LDS (bf16) ----
  {
    int o = lane & 31, fh = lane >> 5;
    const float* wrow = cw1 + o * CO0;           // L1-resident (4 KB)
    float bias = cb1[o];
    float h[8];
#pragma unroll
    for (int j = 0; j < 8; ++j) {
      float hh = bias;
#pragma unroll
      for (int c4 = 0; c4 < 8; ++c4) {
        float4 xv = *(const float4*)&xls[pl * 576 + (fh * 8 + j) * 36 + c4 * 4];
        float4 w  = *(const float4*)(wrow + c4 * 4);
        hh += w.x * xv.x + w.y * xv.y + w.z * xv.z + w.w * xv.w;
      }
      h[j] = leaky(hh);
    }
    if (fh == 1) h[7] = 0.f;                     // cf slot f==15 pad
    union { __hip_bfloat16 hb[8]; uint4 u; } pk;
#pragma unroll
    for (int j = 0; j < 8; ++j) pk.hb[j] = __float2bfloat16(h[j]);
    *(uint4*)(hT + pl * 520 + o * 16 + fh * 8) = pk.u;
  }

  // ---- stage 3: blur GEMM y0 = leaky(W0 h + b0), W0r chunked through LDS ----
  int og = tid & 15, bpl = (tid >> 4) & 3, rep = tid >> 6;
  float acc[4] = {};
  for (int kc = 0; kc < 512; kc += 32) {
    __syncthreads();                             // protect wch (and first: xls readers done)
    for (int e = tid; e < 512; e += 256) {       // 32 rows x 16 float4
      int rr = e >> 4, c4 = e & 15;
      *(float4*)&wch[rr * 68 + c4 * 4] = *(const float4*)(W0r + (size_t)(kc + rr) * 64 + c4 * 4);
    }
    __syncthreads();
#pragma unroll
    for (int i = 0; i < 8; ++i) {
      int kk = rep + i * 4;
      float hv = __bfloat162float(hT[bpl * 520 + kc + kk]);
      float4 w = *(const float4*)&wch[kk * 68 + og * 4];
      acc[0] += w.x * hv; acc[1] += w.y * hv; acc[2] += w.z * hv; acc[3] += w.w * hv;
    }
  }
  __syncthreads();
  *(float4*)&parts[((rep * 4 + bpl) * 16 + og) * 4] = make_float4(acc[0], acc[1], acc[2], acc[3]);
  __syncthreads();

  {
    int ypl = tid & 3, yo3 = tid >> 2;
    int og2 = yo3 >> 2, comp = yo3 & 3;
    float y0 = bb0[yo3];
#pragma unroll
    for (int rp = 0; rp < 4; ++rp)
      y0 += parts[((rp * 4 + ypl) * 16 + og2) * 4 + comp];
    y0s[ypl * 68 + yo3] = leaky(y0);
  }
  __syncthreads();

  // ---- stage 4: final 1x1 (no relu), direct store ----
  {
    int fpl = tid & 3, fo1 = tid >> 2;
    const float* w1row = bw1 + fo1 * 64;         // L1/L2-resident (16 KB)
    float y1 = bb1[fo1];
#pragma unroll
    for (int c4 = 0; c4 < 16; ++c4) {
      float4 w = *(const float4*)(w1row + c4 * 4);
      y1 += w.x * y0s[fpl * 68 + c4 * 4 + 0] + w.y * y0s[fpl * 68 + c4 * 4 + 1] +
            w.z * y0s[fpl * 68 + c4 * 4 + 2] + w.w * y0s[fpl * 68 + c4 * 4 + 3];
    }
    out[((size_t)(b * O1 + fo1)) * M1 + n0 + fpl] = y1;
  }
}

}  // namespace

extern "C" void kernel_launch(void* const* d_in, const int* in_sizes, int n_in,
                              void* d_out, int out_size, void* d_ws, size_t ws_size,
                              hipStream_t stream) {
  const float* feat1 = (const float*)d_in[0];
  const float* feat2 = (const float*)d_in[1];
  const float* prev  = (const float*)d_in[2];
  const float* bary  = (const float*)d_in[3];
  const float* cw0   = (const float*)d_in[4];
  const float* cb0   = (const float*)d_in[5];
  const float* cw1   = (const float*)d_in[6];
  const float* cb1   = (const float*)d_in[7];
  const float* bw0   = (const float*)d_in[8];
  const float* bb0   = (const float*)d_in[9];
  const float* bw1   = (const float*)d_in[10];
  const float* bb1   = (const float*)d_in[11];
  const int* lo  = (const int*)d_in[12];
  const int* pc1 = (const int*)d_in[13];
  const int* pc2 = (const int*)d_in[14];

  float* ws = (float*)d_ws;
  float* splat1 = ws + OFF_SP1;
  float* splat2 = ws + OFF_SP2;
  __hip_bfloat16* Pt = (__hip_bfloat16*)(ws + OFF_P);
  __hip_bfloat16* Qt = (__hip_bfloat16*)(ws + OFF_Q);
  float* cwT   = ws + OFF_CWT;
  float* W0r   = ws + OFF_W0R;
  float* prevT = ws + OFF_PREVT;
  int* counts  = (int*)(ws + OFF_CNT);
  int* rec     = (int*)(ws + OFF_REC);
  unsigned int* gT = (unsigned int*)(ws + OFF_GT);
  float* out   = (float*)d_out;

  hipMemsetAsync(counts, 0, NSLOT * sizeof(int), stream);

  hipLaunchKernelGGL(k_pre, dim3(1243 + 2048), dim3(256), 0, stream,
                     lo, prev, cw0, bw0, pc1, pc2, counts, rec, prevT, cwT, W0r, gT);
  hipLaunchKernelGGL(k_sum, dim3((NSLOT + 3) / 4), dim3(256), 0, stream,
                     rec, counts, bary, prevT, feat1, feat2, splat1, splat2);
  hipLaunchKernelGGL(k_pq, dim3((MS + 63) / 64, CORR, B), dim3(256), 0, stream,
                     splat1, splat2, cwT, Pt, Qt);
  hipLaunchKernelGGL(k_gather, dim3(B * M1 / 4), dim3(256), 0, stream,
                     Pt, Qt, gT, cw1, cb0, cb1, W0r, bb0, bw1, bb1, out);
}